// Round 1
// baseline (9868.023 us; speedup 1.0000x reference)
//
#include <hip/hip_runtime.h>
#include <math.h>

// NeighborGatedAttention: L=2, B=8192, NNEI=128, EMB=HID=128, fp32 throughout.
// One block per b; both layers fused; d_out used as inter-layer x buffer.
// out-proj folded: out = P @ (v @ W_out)  (VW precomputed per b,layer).

constexpr float F_SHIFT   = 20.0f;
constexpr float F_SCALING = 0.08838834764831845f; // 128^-0.5
constexpr float F_LNEPS   = 1e-5f;

// LDS layout (float offsets). Total 40704 floats = 162816 B (<= 160 KiB)
constexpr int KS_OFF  = 0;                    // k   [128][132], col XOR-swizzled by row
constexpr int VW_OFF  = 128 * 132;            // v -> VW [128][132], self col-swizzle
constexpr int SB_OFF  = 2 * 128 * 132;        // W K-tile [16][128]
constexpr int QT_OFF  = SB_OFF + 16 * 128;    // q-tile -> P-tile [32][132]
constexpr int RX_OFF  = QT_OFF + 32 * 132;
constexpr int RY_OFF  = RX_OFF + 128;
constexpr int RZ_OFF  = RY_OFF + 128;
constexpr int SWV_OFF = RZ_OFF + 128;
constexpr int MK_OFF  = SWV_OFF + 128;
constexpr int LDS_FLOATS = MK_OFF + 128;      // 40704

__device__ __forceinline__ void stage_sb(float* sb, const float* __restrict__ W,
                                         int wstride, int cbase, int kt, int t) {
  const int jl = t >> 4;            // 0..15
  const int c0 = (t & 15) << 3;     // 0..120
  const float* s = W + (size_t)(16 * kt + jl) * wstride + cbase + c0;
  const float4 a = *(const float4*)s;
  const float4 b = *(const float4*)(s + 4);
  *(float4*)&sb[jl * 128 + c0]     = a;
  *(float4*)&sb[jl * 128 + c0 + 4] = b;
}

// 128x128 output GEMM, K=128. Thread (rg = t>>3, c8 = t&7):
// rows {rg + 32*rr}, cols {4*c8 + 32*g + w}. acc[4][16].
// Source: global (row stride 128) or LDS [128][132] with self col-swizzle.
template <bool SRC_LDS>
__device__ __forceinline__ void big_gemm(float acc[4][16],
    const float* __restrict__ gsrc, const float* lsrc,
    const float* __restrict__ W, int wstride, int cbase,
    float* sb, int t)
{
  const int rg = t >> 3;
  const int c8 = t & 7;
#pragma unroll
  for (int rr = 0; rr < 4; ++rr)
#pragma unroll
    for (int i = 0; i < 16; ++i) acc[rr][i] = 0.0f;

  for (int kt = 0; kt < 8; ++kt) {
    __syncthreads();
    stage_sb(sb, W, wstride, cbase, kt, t);
    __syncthreads();
#pragma unroll
    for (int j0 = 0; j0 < 16; j0 += 4) {
      float xv[4][4];
#pragma unroll
      for (int rr = 0; rr < 4; ++rr) {
        const int row = rg + 32 * rr;
        float4 v;
        if constexpr (SRC_LDS) {
          const int j = 16 * kt + j0;
          v = *(const float4*)&lsrc[row * 132 + (j ^ (4 * ((j >> 5) & 3)))];
        } else {
          v = *(const float4*)&gsrc[(size_t)row * 128 + 16 * kt + j0];
        }
        xv[rr][0] = v.x; xv[rr][1] = v.y; xv[rr][2] = v.z; xv[rr][3] = v.w;
      }
#pragma unroll
      for (int jj = 0; jj < 4; ++jj) {
#pragma unroll
        for (int g = 0; g < 4; ++g) {
          const float4 wv = *(const float4*)&sb[(j0 + jj) * 128 + 4 * c8 + 32 * g];
#pragma unroll
          for (int rr = 0; rr < 4; ++rr) {
            acc[rr][4 * g + 0] = fmaf(xv[rr][jj], wv.x, acc[rr][4 * g + 0]);
            acc[rr][4 * g + 1] = fmaf(xv[rr][jj], wv.y, acc[rr][4 * g + 1]);
            acc[rr][4 * g + 2] = fmaf(xv[rr][jj], wv.z, acc[rr][4 * g + 2]);
            acc[rr][4 * g + 3] = fmaf(xv[rr][jj], wv.w, acc[rr][4 * g + 3]);
          }
        }
      }
    }
  }
}

__global__ __launch_bounds__(256, 1)
void ngatt_kernel(const float* __restrict__ G, const int* __restrict__ nmask,
                  const float* __restrict__ r3, const float* __restrict__ swg,
                  const float* __restrict__ Win, const float* __restrict__ bin,
                  const float* __restrict__ Wout, const float* __restrict__ bout,
                  const float* __restrict__ lng, const float* __restrict__ lnb,
                  float* __restrict__ xout)
{
  extern __shared__ float lds[];
  float* ks  = lds + KS_OFF;
  float* vw  = lds + VW_OFF;
  float* sb  = lds + SB_OFF;
  float* qt  = lds + QT_OFF;
  float* rxv = lds + RX_OFF;
  float* ryv = lds + RY_OFF;
  float* rzv = lds + RZ_OFF;
  float* swv = lds + SWV_OFF;
  float* mkv = lds + MK_OFF;

  const int b = blockIdx.x;
  const int t = threadIdx.x;
  const size_t bbase = (size_t)b * 128 * 128;

  if (t < 128) {
    const size_t gi = (size_t)b * 128 + t;
    rxv[t] = r3[gi * 3 + 0];
    ryv[t] = r3[gi * 3 + 1];
    rzv[t] = r3[gi * 3 + 2];
    swv[t] = swg[gi];
    mkv[t] = (nmask[gi] != 0) ? 1.0f : 0.0f;
  }
  __syncthreads();

  for (int l = 0; l < 2; ++l) {
    const float* xsrc = (l == 0) ? (G + bbase) : (xout + bbase);
    const float* Wl = Win + (size_t)l * 128 * 384;
    const float* bl = bin + l * 384;
    const float* Wo = Wout + (size_t)l * 128 * 128;
    const float* bo = bout + l * 128;
    const float* gl = lng + l * 128;
    const float* be = lnb + l * 128;

    // ---------- k and v GEMMs (normalized rows into LDS) ----------
    for (int which = 0; which < 2; ++which) {
      float acc[4][16];
      big_gemm<false>(acc, xsrc, nullptr, Wl, 384, 128 + 128 * which, sb, t);
      const int rg = t >> 3, c8 = t & 7;
      const float* bias = bl + 128 + 128 * which;
#pragma unroll
      for (int rr = 0; rr < 4; ++rr) {
        float ss = 0.0f;
#pragma unroll
        for (int g = 0; g < 4; ++g)
#pragma unroll
          for (int w = 0; w < 4; ++w) {
            const float v = acc[rr][4 * g + w] + bias[4 * c8 + 32 * g + w];
            acc[rr][4 * g + w] = v;
            ss += v * v;
          }
        ss += __shfl_xor(ss, 1); ss += __shfl_xor(ss, 2); ss += __shfl_xor(ss, 4);
        const float inv = 1.0f / fmaxf(sqrtf(ss), 1e-12f);
        const int n = rg + 32 * rr;
#pragma unroll
        for (int g = 0; g < 4; ++g) {
          const int c = 4 * c8 + 32 * g;
          const float4 st = make_float4(acc[rr][4 * g] * inv, acc[rr][4 * g + 1] * inv,
                                        acc[rr][4 * g + 2] * inv, acc[rr][4 * g + 3] * inv);
          if (which == 0) *(float4*)&ks[n * 132 + (c ^ (4 * ((n >> 3) & 7)))] = st;
          else            *(float4*)&vw[n * 132 + (c ^ (4 * ((c >> 5) & 3)))] = st;
        }
      }
      __syncthreads();
    }

    // ---------- VW = v @ Wout (in place over v; acc fully in regs first) ----------
    {
      float acc[4][16];
      big_gemm<true>(acc, nullptr, vw, Wo, 128, 0, sb, t);
      __syncthreads();  // all v reads complete before overwrite
      const int rg = t >> 3, c8 = t & 7;
#pragma unroll
      for (int rr = 0; rr < 4; ++rr) {
        const int n = rg + 32 * rr;
#pragma unroll
        for (int g = 0; g < 4; ++g) {
          const int c = 4 * c8 + 32 * g;
          const float4 st = make_float4(acc[rr][4 * g], acc[rr][4 * g + 1],
                                        acc[rr][4 * g + 2], acc[rr][4 * g + 3]);
          *(float4*)&vw[n * 132 + (c ^ (4 * ((c >> 5) & 3)))] = st;
        }
      }
      __syncthreads();
    }

    // ---------- per 32-row q-tile: q -> S -> softmax*factors -> P -> P@VW -> LN ----------
    for (int qtile = 0; qtile < 4; ++qtile) {
      const int rp = t >> 4;   // 0..15
      const int eg = t & 15;   // 0..15

      // q GEMM: rows {32*qtile + rp, +16}, cols {4eg..+3} u {64+4eg..+3}
      float qa[2][8];
#pragma unroll
      for (int rr = 0; rr < 2; ++rr)
#pragma unroll
        for (int i = 0; i < 8; ++i) qa[rr][i] = 0.0f;

      for (int kt = 0; kt < 8; ++kt) {
        __syncthreads();
        stage_sb(sb, Wl, 384, 0, kt, t);
        __syncthreads();
#pragma unroll
        for (int j0 = 0; j0 < 16; j0 += 4) {
          float xq[2][4];
#pragma unroll
          for (int rr = 0; rr < 2; ++rr) {
            const int row = 32 * qtile + rp + 16 * rr;
            const float4 xv = *(const float4*)&xsrc[(size_t)row * 128 + 16 * kt + j0];
            xq[rr][0] = xv.x; xq[rr][1] = xv.y; xq[rr][2] = xv.z; xq[rr][3] = xv.w;
          }
#pragma unroll
          for (int jj = 0; jj < 4; ++jj) {
            const float4 w0 = *(const float4*)&sb[(j0 + jj) * 128 + 4 * eg];
            const float4 w1 = *(const float4*)&sb[(j0 + jj) * 128 + 64 + 4 * eg];
#pragma unroll
            for (int rr = 0; rr < 2; ++rr) {
              qa[rr][0] = fmaf(xq[rr][jj], w0.x, qa[rr][0]);
              qa[rr][1] = fmaf(xq[rr][jj], w0.y, qa[rr][1]);
              qa[rr][2] = fmaf(xq[rr][jj], w0.z, qa[rr][2]);
              qa[rr][3] = fmaf(xq[rr][jj], w0.w, qa[rr][3]);
              qa[rr][4] = fmaf(xq[rr][jj], w1.x, qa[rr][4]);
              qa[rr][5] = fmaf(xq[rr][jj], w1.y, qa[rr][5]);
              qa[rr][6] = fmaf(xq[rr][jj], w1.z, qa[rr][6]);
              qa[rr][7] = fmaf(xq[rr][jj], w1.w, qa[rr][7]);
            }
          }
        }
      }
      // bias + l2norm * scaling
#pragma unroll
      for (int rr = 0; rr < 2; ++rr) {
        float ss = 0.0f;
#pragma unroll
        for (int i = 0; i < 4; ++i) { const float v = qa[rr][i] + bl[4 * eg + i]; qa[rr][i] = v; ss += v * v; }
#pragma unroll
        for (int i = 0; i < 4; ++i) { const float v = qa[rr][4 + i] + bl[64 + 4 * eg + i]; qa[rr][4 + i] = v; ss += v * v; }
        ss += __shfl_xor(ss, 1); ss += __shfl_xor(ss, 2);
        ss += __shfl_xor(ss, 4); ss += __shfl_xor(ss, 8);
        const float inv = F_SCALING / fmaxf(sqrtf(ss), 1e-12f);
#pragma unroll
        for (int i = 0; i < 8; ++i) qa[rr][i] *= inv;
      }
      __syncthreads();
#pragma unroll
      for (int rr = 0; rr < 2; ++rr) {
        const int r = rp + 16 * rr;
        *(float4*)&qt[r * 132 + 4 * eg]      = make_float4(qa[rr][0], qa[rr][1], qa[rr][2], qa[rr][3]);
        *(float4*)&qt[r * 132 + 64 + 4 * eg] = make_float4(qa[rr][4], qa[rr][5], qa[rr][6], qa[rr][7]);
      }
      __syncthreads();

      // S = q @ k^T : thread (rp, mg=eg): rows {rp, rp+16}, m in {8*eg..+8}
      float sacc[2][8];
#pragma unroll
      for (int rr = 0; rr < 2; ++rr)
#pragma unroll
        for (int i = 0; i < 8; ++i) sacc[rr][i] = 0.0f;
      const int jx = 4 * (eg & 7);  // = 4*((m>>3)&7) for m = 8*eg+mm
#pragma unroll 2
      for (int j0 = 0; j0 < 128; j0 += 4) {
        float qv[2][4];
#pragma unroll
        for (int rr = 0; rr < 2; ++rr) {
          const float4 v = *(const float4*)&qt[(rp + 16 * rr) * 132 + j0];
          qv[rr][0] = v.x; qv[rr][1] = v.y; qv[rr][2] = v.z; qv[rr][3] = v.w;
        }
#pragma unroll
        for (int mm = 0; mm < 8; ++mm) {
          const int m = 8 * eg + mm;
          const float4 kv = *(const float4*)&ks[m * 132 + (j0 ^ jx)];
#pragma unroll
          for (int rr = 0; rr < 2; ++rr) {
            sacc[rr][mm] += qv[rr][0] * kv.x + qv[rr][1] * kv.y
                          + qv[rr][2] * kv.z + qv[rr][3] * kv.w;
          }
        }
      }

      // softmax((S+SHIFT)*sw_ij - SHIFT) * mask_n * sw_ij * ang
      float pp[2][8];
#pragma unroll
      for (int rr = 0; rr < 2; ++rr) {
        const int n = 32 * qtile + rp + 16 * rr;
        const float swn = swv[n];
        float lg[8];
        float mx = -1e30f;
#pragma unroll
        for (int mm = 0; mm < 8; ++mm) {
          const int m = 8 * eg + mm;
          lg[mm] = (sacc[rr][mm] + F_SHIFT) * (swn * swv[m]) - F_SHIFT;
          mx = fmaxf(mx, lg[mm]);
        }
        mx = fmaxf(mx, __shfl_xor(mx, 1)); mx = fmaxf(mx, __shfl_xor(mx, 2));
        mx = fmaxf(mx, __shfl_xor(mx, 4)); mx = fmaxf(mx, __shfl_xor(mx, 8));
        float sum = 0.0f;
#pragma unroll
        for (int mm = 0; mm < 8; ++mm) { const float e = __expf(lg[mm] - mx); pp[rr][mm] = e; sum += e; }
        sum += __shfl_xor(sum, 1); sum += __shfl_xor(sum, 2);
        sum += __shfl_xor(sum, 4); sum += __shfl_xor(sum, 8);
        const float fac = mkv[n] / sum;
        const float rxn = rxv[n], ryn = ryv[n], rzn = rzv[n];
#pragma unroll
        for (int mm = 0; mm < 8; ++mm) {
          const int m = 8 * eg + mm;
          const float ang = rxn * rxv[m] + ryn * ryv[m] + rzn * rzv[m];
          pp[rr][mm] *= fac * (swn * swv[m]) * ang;
        }
      }
      __syncthreads();  // all q reads done; P overwrites qt
#pragma unroll
      for (int rr = 0; rr < 2; ++rr) {
        const int r = rp + 16 * rr;
        *(float4*)&qt[r * 132 + 8 * eg]     = make_float4(pp[rr][0], pp[rr][1], pp[rr][2], pp[rr][3]);
        *(float4*)&qt[r * 132 + 8 * eg + 4] = make_float4(pp[rr][4], pp[rr][5], pp[rr][6], pp[rr][7]);
      }
      __syncthreads();

      // out = P @ VW : thread (rp, eg): rows {rp, rp+16}, cols {4eg..+3} u {64+4eg..+3}
      float oa[2][8];
#pragma unroll
      for (int rr = 0; rr < 2; ++rr)
#pragma unroll
        for (int i = 0; i < 8; ++i) oa[rr][i] = 0.0f;
      const int c0 = 4 * eg;
      const int p0 = c0 ^ (4 * ((c0 >> 5) & 3));
      const int c1 = 64 + 4 * eg;
      const int p1 = c1 ^ (4 * ((c1 >> 5) & 3));
#pragma unroll 2
      for (int m0 = 0; m0 < 128; m0 += 4) {
        float pv[2][4];
#pragma unroll
        for (int rr = 0; rr < 2; ++rr) {
          const float4 v = *(const float4*)&qt[(rp + 16 * rr) * 132 + m0];
          pv[rr][0] = v.x; pv[rr][1] = v.y; pv[rr][2] = v.z; pv[rr][3] = v.w;
        }
#pragma unroll
        for (int mm = 0; mm < 4; ++mm) {
          const int m = m0 + mm;
          const float4 w0 = *(const float4*)&vw[m * 132 + p0];
          const float4 w1 = *(const float4*)&vw[m * 132 + p1];
#pragma unroll
          for (int rr = 0; rr < 2; ++rr) {
            oa[rr][0] = fmaf(pv[rr][mm], w0.x, oa[rr][0]);
            oa[rr][1] = fmaf(pv[rr][mm], w0.y, oa[rr][1]);
            oa[rr][2] = fmaf(pv[rr][mm], w0.z, oa[rr][2]);
            oa[rr][3] = fmaf(pv[rr][mm], w0.w, oa[rr][3]);
            oa[rr][4] = fmaf(pv[rr][mm], w1.x, oa[rr][4]);
            oa[rr][5] = fmaf(pv[rr][mm], w1.y, oa[rr][5]);
            oa[rr][6] = fmaf(pv[rr][mm], w1.z, oa[rr][6]);
            oa[rr][7] = fmaf(pv[rr][mm], w1.w, oa[rr][7]);
          }
        }
      }

      // epilogue: + b_out + residual, LayerNorm, write x'
#pragma unroll
      for (int rr = 0; rr < 2; ++rr) {
        const int n = 32 * qtile + rp + 16 * rr;
        const float* xr = xsrc + (size_t)n * 128;
        const float4 x0 = *(const float4*)&xr[4 * eg];
        const float4 x1 = *(const float4*)&xr[64 + 4 * eg];
        float v[8];
        v[0] = oa[rr][0] + bo[4 * eg + 0] + x0.x;
        v[1] = oa[rr][1] + bo[4 * eg + 1] + x0.y;
        v[2] = oa[rr][2] + bo[4 * eg + 2] + x0.z;
        v[3] = oa[rr][3] + bo[4 * eg + 3] + x0.w;
        v[4] = oa[rr][4] + bo[64 + 4 * eg + 0] + x1.x;
        v[5] = oa[rr][5] + bo[64 + 4 * eg + 1] + x1.y;
        v[6] = oa[rr][6] + bo[64 + 4 * eg + 2] + x1.z;
        v[7] = oa[rr][7] + bo[64 + 4 * eg + 3] + x1.w;
        float s1 = 0.0f, s2 = 0.0f;
#pragma unroll
        for (int i = 0; i < 8; ++i) { s1 += v[i]; s2 += v[i] * v[i]; }
        s1 += __shfl_xor(s1, 1); s1 += __shfl_xor(s1, 2);
        s1 += __shfl_xor(s1, 4); s1 += __shfl_xor(s1, 8);
        s2 += __shfl_xor(s2, 1); s2 += __shfl_xor(s2, 2);
        s2 += __shfl_xor(s2, 4); s2 += __shfl_xor(s2, 8);
        const float mu = s1 * (1.0f / 128.0f);
        const float var = s2 * (1.0f / 128.0f) - mu * mu;
        const float rs = rsqrtf(var + F_LNEPS);
        float y[8];
#pragma unroll
        for (int i = 0; i < 4; ++i)
          y[i] = (v[i] - mu) * rs * gl[4 * eg + i] + be[4 * eg + i];
#pragma unroll
        for (int i = 0; i < 4; ++i)
          y[4 + i] = (v[4 + i] - mu) * rs * gl[64 + 4 * eg + i] + be[64 + 4 * eg + i];
        float* orow = xout + bbase + (size_t)n * 128;
        *(float4*)&orow[4 * eg]      = make_float4(y[0], y[1], y[2], y[3]);
        *(float4*)&orow[64 + 4 * eg] = make_float4(y[4], y[5], y[6], y[7]);
      }
      __syncthreads();  // qt reused next qtile
    } // qtile
    __syncthreads();    // layer boundary (ks/vw reused)
  } // layer
}

extern "C" void kernel_launch(void* const* d_in, const int* in_sizes, int n_in,
                              void* d_out, int out_size, void* d_ws, size_t ws_size,
                              hipStream_t stream) {
  const float* G    = (const float*)d_in[0];
  const int*   msk  = (const int*)d_in[1];
  const float* r3   = (const float*)d_in[2];
  const float* swg  = (const float*)d_in[3];
  const float* Win  = (const float*)d_in[4];
  const float* bin  = (const float*)d_in[5];
  const float* Wout = (const float*)d_in[6];
  const float* bout = (const float*)d_in[7];
  const float* lng  = (const float*)d_in[8];
  const float* lnb  = (const float*)d_in[9];
  float* xout = (float*)d_out;

  const int B = in_sizes[0] / (128 * 128);
  const int ldsBytes = LDS_FLOATS * (int)sizeof(float);

  // Opt in to >64KB dynamic LDS (idempotent; host-side, graph-capture safe).
  hipFuncSetAttribute((const void*)ngatt_kernel,
                      hipFuncAttributeMaxDynamicSharedMemorySize, ldsBytes);

  ngatt_kernel<<<dim3(B), dim3(256), ldsBytes, stream>>>(
      G, msk, r3, swg, Win, bin, Wout, bout, lng, lnb, xout);
}

// Round 2
// 2565.837 us; speedup vs baseline: 3.8459x; 3.8459x over previous
//
#include <hip/hip_runtime.h>
#include <math.h>

// NeighborGatedAttention, bf16-MFMA version.
// L=2, B=8192, NNEI=128, EMB=HID=128. One block (512 thr = 8 waves) per b.
// All GEMMs: v_mfma_f32_16x16x32_bf16 (A: row=l%16,k=8*(l/16)+i; B: col=l%16,
// k=8*(l/16)+i; C/D: col=l&15, row=4*(l>>4)+reg  [learn_hip m89-verified]).
// l2-norms computed from fp32 accs and folded into S/P epilogues (stay fp32).

typedef __attribute__((ext_vector_type(8))) short bf16x8; // 8 bf16 = 4 VGPR
typedef __attribute__((ext_vector_type(4))) float f32x4;
typedef unsigned short ushort_t;
typedef unsigned int uint_t;

constexpr float F_SHIFT   = 20.0f;
constexpr float F_SCALING = 0.08838834764831845f; // 128^-0.5
constexpr float F_LNEPS   = 1e-5f;

constexpr int ROWP = 136;                 // ushort row pitch (272B) for big bufs
constexpr int BUF_US = 128 * ROWP;        // 17408 ushorts per buffer
constexpr size_t WTI_ELEMS = 2 * 384 * 128;
constexpr size_t WTO_ELEMS = 2 * 128 * 128;
constexpr int LDS_BYTES = 3 * BUF_US * 2 + (4 * 128 + 2 * 128 + 8 * 128) * 4; // 111616

#define MFMA(a, b, c) __builtin_amdgcn_mfma_f32_16x16x32_bf16(a, b, c, 0, 0, 0)

__device__ __forceinline__ ushort_t f2bf(float f) {
  uint_t u = __float_as_uint(f);
  u += 0x7FFFu + ((u >> 16) & 1u);        // RNE
  return (ushort_t)(u >> 16);
}

// A/B fragment from pre-transposed bf16 weights (WS) or fp32 gather fallback.
// WS layout: wt[r][c] row-major pitch 128.  Fallback: wt[r][c] == W[c][r], ld=ldW.
template <bool WS>
__device__ __forceinline__ bf16x8 wt_frag(const ushort_t* __restrict__ wt,
                                          const float* __restrict__ W,
                                          int r, int c, int ldW) {
  if constexpr (WS) {
    return *(const bf16x8*)(wt + r * 128 + c);
  } else {
    bf16x8 f;
#pragma unroll
    for (int j = 0; j < 8; ++j) f[j] = (short)f2bf(W[(size_t)(c + j) * ldW + r]);
    return f;
  }
}

__global__ void prep_weights(const float* __restrict__ Win, const float* __restrict__ Wout,
                             ushort_t* __restrict__ wtI, ushort_t* __restrict__ wtO) {
  const int i = blockIdx.x * 256 + threadIdx.x;
  if (i < (int)WTI_ELEMS) {   // wtI[l][h][e] = bf16(Win[l][e][h])   (384x128 per layer)
    const int l = i / (384 * 128), r = i % (384 * 128), h = r >> 7, e = r & 127;
    wtI[i] = f2bf(Win[l * (128 * 384) + e * 384 + h]);
  }
  if (i < (int)WTO_ELEMS) {   // wtO[l][e][h] = bf16(Wout[l][h][e])  (128x128 per layer)
    const int l = i >> 14, r = i & 16383, e = r >> 7, h = r & 127;
    wtO[i] = f2bf(Wout[(l << 14) + h * 128 + e]);
  }
}

__device__ __forceinline__ void qkv_epi(int ht, const f32x4& acc,
                                        const float* __restrict__ binL,
                                        int n_mine, int lg,
                                        ushort_t* bufQ, ushort_t* bufK, ushort_t* bufV,
                                        float& ssq, float& ssk, float& ssv) {
  const int hb = 16 * (ht & 7) + 4 * lg;
  const float4 bi = *(const float4*)&binL[16 * ht + 4 * lg];
  const float v0 = acc[0] + bi.x, v1 = acc[1] + bi.y, v2 = acc[2] + bi.z, v3 = acc[3] + bi.w;
  const float ssl = v0 * v0 + v1 * v1 + v2 * v2 + v3 * v3;
  const ushort4 pk = make_ushort4(f2bf(v0), f2bf(v1), f2bf(v2), f2bf(v3));
  ushort_t* dst;
  if (ht < 8)       { ssq += ssl; dst = bufQ; }
  else if (ht < 16) { ssk += ssl; dst = bufK; }
  else              { ssv += ssl; dst = bufV; }
  *(ushort4*)(dst + n_mine * ROWP + hb) = pk;
}

template <bool WS>
__global__ __launch_bounds__(512, 2)
void ngatt_mfma(const float* __restrict__ G, const int* __restrict__ nmask,
                const float* __restrict__ r3, const float* __restrict__ swg,
                const float* __restrict__ Win, const float* __restrict__ bin,
                const float* __restrict__ Wout, const float* __restrict__ bout,
                const float* __restrict__ lng, const float* __restrict__ lnb,
                const ushort_t* __restrict__ wtin, const ushort_t* __restrict__ wtout,
                float* __restrict__ xout) {
  extern __shared__ char smem[];
  ushort_t* bufQ = (ushort_t*)smem;            // q, then P
  ushort_t* bufK = bufQ + BUF_US;              // k
  ushort_t* bufV = bufK + BUF_US;              // v, then VW^T
  float* fA  = (float*)(bufV + BUF_US);        // [128] float4: {invk*SCALING, sw, invv, rx}
  float* fB  = fA + 4 * 128;                   // [128] float2: {ry, rz}
  float* sSW = fB + 2 * 128;
  float* sMK = sSW + 128;
  float* sRX = sMK + 128; float* sRY = sRX + 128; float* sRZ = sRY + 128;
  float* sIQ = sRZ + 128; float* sIK = sIQ + 128; float* sIV = sIK + 128;

  const int b = blockIdx.x, t = threadIdx.x;
  const int w = t >> 6, l = t & 63, lc = l & 15, lg = l >> 4;
  const size_t bb = (size_t)b * (128 * 128);
  const int n_mine = 16 * w + lc;   // this lane's column (n) in swapped gemms

  if (t < 128) {
    const size_t gi = (size_t)b * 128 + t;
    sSW[t] = swg[gi];
    sMK[t] = nmask[gi] ? 1.0f : 0.0f;
    sRX[t] = r3[gi * 3 + 0]; sRY[t] = r3[gi * 3 + 1]; sRZ[t] = r3[gi * 3 + 2];
  }
  __syncthreads();

  for (int layer = 0; layer < 2; ++layer) {
    const float* xsrc = layer ? (xout + bb) : (G + bb);
    const ushort_t* wtI = wtin + (size_t)layer * 384 * 128;
    const ushort_t* wtO = wtout + (size_t)layer * 128 * 128;
    const float* WinL  = Win  + (size_t)layer * 128 * 384;
    const float* WoutL = Wout + (size_t)layer * 128 * 128;
    const float* binL  = bin  + layer * 384;
    const float* boutL = bout + layer * 128;
    const float* lngL  = lng  + layer * 128;
    const float* lnbL  = lnb  + layer * 128;

    // ---- hoist x B-fragments (global fp32 -> bf16), reused for all 24 row-tiles ----
    bf16x8 xf[4];
    {
      const float* xr = xsrc + (size_t)n_mine * 128 + 8 * lg;
#pragma unroll
      for (int kk = 0; kk < 4; ++kk) {
        const float4 a = *(const float4*)(xr + 32 * kk);
        const float4 c = *(const float4*)(xr + 32 * kk + 4);
        bf16x8 f;
        f[0] = (short)f2bf(a.x); f[1] = (short)f2bf(a.y);
        f[2] = (short)f2bf(a.z); f[3] = (short)f2bf(a.w);
        f[4] = (short)f2bf(c.x); f[5] = (short)f2bf(c.y);
        f[6] = (short)f2bf(c.z); f[7] = (short)f2bf(c.w);
        xf[kk] = f;
      }
    }

    // ---- qkv^T gemm: D = W_in^T(384x128) * x^T ; paired tiles (j, j+12), prefetch-1 ----
    float ssq = 0.f, ssk = 0.f, ssv = 0.f;
    {
      bf16x8 awA[4], awB[4], nwA[4], nwB[4];
#pragma unroll
      for (int kk = 0; kk < 4; ++kk) {
        awA[kk] = wt_frag<WS>(wtI, WinL, lc,           8 * lg + 32 * kk, 384);
        awB[kk] = wt_frag<WS>(wtI, WinL, 16 * 12 + lc, 8 * lg + 32 * kk, 384);
      }
      for (int j = 0; j < 12; ++j) {
        if (j < 11) {
#pragma unroll
          for (int kk = 0; kk < 4; ++kk) {
            nwA[kk] = wt_frag<WS>(wtI, WinL, 16 * (j + 1)  + lc, 8 * lg + 32 * kk, 384);
            nwB[kk] = wt_frag<WS>(wtI, WinL, 16 * (j + 13) + lc, 8 * lg + 32 * kk, 384);
          }
        }
        f32x4 aA = {0, 0, 0, 0}, aB = {0, 0, 0, 0};
#pragma unroll
        for (int kk = 0; kk < 4; ++kk) {
          aA = MFMA(awA[kk], xf[kk], aA);
          aB = MFMA(awB[kk], xf[kk], aB);
        }
        qkv_epi(j,      aA, binL, n_mine, lg, bufQ, bufK, bufV, ssq, ssk, ssv);
        qkv_epi(j + 12, aB, binL, n_mine, lg, bufQ, bufK, bufV, ssq, ssk, ssv);
#pragma unroll
        for (int kk = 0; kk < 4; ++kk) { awA[kk] = nwA[kk]; awB[kk] = nwB[kk]; }
      }
    }
    // row-norm sums: lanes lg=0..3 hold disjoint h-subsets of row n_mine
    ssq += __shfl_xor(ssq, 16); ssq += __shfl_xor(ssq, 32);
    ssk += __shfl_xor(ssk, 16); ssk += __shfl_xor(ssk, 32);
    ssv += __shfl_xor(ssv, 16); ssv += __shfl_xor(ssv, 32);
    sIQ[n_mine] = 1.0f / fmaxf(sqrtf(ssq), 1e-12f);
    sIK[n_mine] = 1.0f / fmaxf(sqrtf(ssk), 1e-12f);
    sIV[n_mine] = 1.0f / fmaxf(sqrtf(ssv), 1e-12f);
    __syncthreads();   // B1: q,k,v + inv arrays complete

    // compose softmax factor tables
    if (t < 128) {
      fA[4 * t + 0] = sIK[t] * F_SCALING;
      fA[4 * t + 1] = sSW[t];
      fA[4 * t + 2] = sIV[t];
      fA[4 * t + 3] = sRX[t];
      fB[2 * t + 0] = sRY[t];
      fB[2 * t + 1] = sRZ[t];
    }
    // hoist v A-fragments (wave w owns VW rows 16w..16w+15)
    bf16x8 vf[4];
#pragma unroll
    for (int kk = 0; kk < 4; ++kk)
      vf[kk] = *(const bf16x8*)(bufV + (16 * w + lc) * ROWP + 8 * lg + 32 * kk);
    __syncthreads();   // B2: all v-frags hoisted; VW^T may overwrite bufV

    // ---- VW = v @ W_out, stored as VW^T into bufV; paired e-tiles, prefetch-1 ----
    {
      bf16x8 bwA[4], bwB[4], nbA[4], nbB[4];
#pragma unroll
      for (int kk = 0; kk < 4; ++kk) {
        bwA[kk] = wt_frag<WS>(wtO, WoutL, lc,          8 * lg + 32 * kk, 128);
        bwB[kk] = wt_frag<WS>(wtO, WoutL, 16 * 4 + lc, 8 * lg + 32 * kk, 128);
      }
      for (int j = 0; j < 4; ++j) {
        if (j < 3) {
#pragma unroll
          for (int kk = 0; kk < 4; ++kk) {
            nbA[kk] = wt_frag<WS>(wtO, WoutL, 16 * (j + 1) + lc, 8 * lg + 32 * kk, 128);
            nbB[kk] = wt_frag<WS>(wtO, WoutL, 16 * (j + 5) + lc, 8 * lg + 32 * kk, 128);
          }
        }
        f32x4 aA = {0, 0, 0, 0}, aB = {0, 0, 0, 0};
#pragma unroll
        for (int kk = 0; kk < 4; ++kk) {
          aA = MFMA(vf[kk], bwA[kk], aA);
          aB = MFMA(vf[kk], bwB[kk], aB);
        }
        // store VW^T[e][m]: e = 16*ct + lc, m = 16*w + 4*lg + reg
#pragma unroll
        for (int h2 = 0; h2 < 2; ++h2) {
          const f32x4& a = h2 ? aB : aA;
          const int e = 16 * (j + 4 * h2) + lc;
          const ushort4 pk = make_ushort4(f2bf(a[0]), f2bf(a[1]), f2bf(a[2]), f2bf(a[3]));
          *(ushort4*)(bufV + e * ROWP + 16 * w + 4 * lg) = pk;
        }
#pragma unroll
        for (int kk = 0; kk < 4; ++kk) { bwA[kk] = nbA[kk]; bwB[kk] = nbB[kk]; }
      }
    }

    // ---- S^T = k * q^T ; wave w owns q-columns n = 16w..16w+15 ----
    bf16x8 qf[4];
#pragma unroll
    for (int kk = 0; kk < 4; ++kk)
      qf[kk] = *(const bf16x8*)(bufQ + n_mine * ROWP + 8 * lg + 32 * kk);
    __syncthreads();   // B3: all q-frags hoisted; P may overwrite bufQ later

    f32x4 sacc[8];
#pragma unroll
    for (int j = 0; j < 4; ++j) {
      bf16x8 kA[4], kB[4];
#pragma unroll
      for (int kk = 0; kk < 4; ++kk) {
        kA[kk] = *(const bf16x8*)(bufK + (16 * j + lc)       * ROWP + 8 * lg + 32 * kk);
        kB[kk] = *(const bf16x8*)(bufK + (16 * (j + 4) + lc) * ROWP + 8 * lg + 32 * kk);
      }
      f32x4 aA = {0, 0, 0, 0}, aB = {0, 0, 0, 0};
#pragma unroll
      for (int kk = 0; kk < 4; ++kk) {
        aA = MFMA(kA[kk], qf[kk], aA);
        aB = MFMA(kB[kk], qf[kk], aB);
      }
      sacc[j] = aA; sacc[j + 4] = aB;
    }

    // ---- softmax * factors, fully in-register (lane owns row n_mine, 32 m's) ----
    {
      const float iqn = sIQ[n_mine];
      const float swn = sSW[n_mine];
      const float rxn = sRX[n_mine], ryn = sRY[n_mine], rzn = sRZ[n_mine];
      const float mkn = sMK[n_mine];
      float sum = 0.0f;
#pragma unroll
      for (int mt = 0; mt < 8; ++mt) {
#pragma unroll
        for (int r2 = 0; r2 < 4; ++r2) {
          const int m = 16 * mt + 4 * lg + r2;
          const float4 a4 = *(const float4*)&fA[4 * m];   // {invk*SCALING, sw, invv, rx}
          const float2 b2 = *(const float2*)&fB[2 * m];   // {ry, rz}
          const float sws = swn * a4.y;
          const float lgt = (sacc[mt][r2] * iqn * a4.x + F_SHIFT) * sws - F_SHIFT;
          const float e = __expf(lgt);   // logits in [-20, 0.09]: no max-sub needed
          sum += e;
          const float ang = rxn * a4.w + ryn * b2.x + rzn * b2.y;
          sacc[mt][r2] = e * sws * a4.z * ang;            // P prefactor (invv folded)
        }
      }
      sum += __shfl_xor(sum, 16); sum += __shfl_xor(sum, 32);
      const float fac = mkn / sum;
#pragma unroll
      for (int mt = 0; mt < 8; ++mt) {
        const ushort4 pk = make_ushort4(f2bf(sacc[mt][0] * fac), f2bf(sacc[mt][1] * fac),
                                        f2bf(sacc[mt][2] * fac), f2bf(sacc[mt][3] * fac));
        *(ushort4*)(bufQ + n_mine * ROWP + 16 * mt + 4 * lg) = pk;
      }
    }
    __syncthreads();   // B4: P + VW^T complete

    // ---- out = P @ VW ; wave w owns output rows 16w..16w+15 ----
    bf16x8 pf[4];
#pragma unroll
    for (int kk = 0; kk < 4; ++kk)
      pf[kk] = *(const bf16x8*)(bufQ + (16 * w + lc) * ROWP + 8 * lg + 32 * kk);
    f32x4 oacc[8];
#pragma unroll
    for (int j = 0; j < 4; ++j) {
      bf16x8 bA[4], bB[4];
#pragma unroll
      for (int kk = 0; kk < 4; ++kk) {
        bA[kk] = *(const bf16x8*)(bufV + (16 * j + lc)       * ROWP + 8 * lg + 32 * kk);
        bB[kk] = *(const bf16x8*)(bufV + (16 * (j + 4) + lc) * ROWP + 8 * lg + 32 * kk);
      }
      f32x4 aA = {0, 0, 0, 0}, aB = {0, 0, 0, 0};
#pragma unroll
      for (int kk = 0; kk < 4; ++kk) {
        aA = MFMA(pf[kk], bA[kk], aA);
        aB = MFMA(pf[kk], bB[kk], aB);
      }
      oacc[j] = aA; oacc[j + 4] = aB;
    }

    // ---- epilogue: +b_out +residual(fp32), LayerNorm over e, write x' ----
    {
      float bo8[8], g8[8], be8[8];
#pragma unroll
      for (int ct = 0; ct < 8; ++ct) {
        const int e = 16 * ct + lc;
        bo8[ct] = boutL[e]; g8[ct] = lngL[e]; be8[ct] = lnbL[e];
      }
#pragma unroll
      for (int r2 = 0; r2 < 4; ++r2) {
        const int n = 16 * w + 4 * lg + r2;
        const float* xr = xsrc + (size_t)n * 128;
        float vals[8];
        float s1 = 0.0f, s2 = 0.0f;
#pragma unroll
        for (int ct = 0; ct < 8; ++ct) {
          const float v = oacc[ct][r2] + bo8[ct] + xr[16 * ct + lc];
          vals[ct] = v; s1 += v; s2 += v * v;
        }
        s1 += __shfl_xor(s1, 1); s1 += __shfl_xor(s1, 2);
        s1 += __shfl_xor(s1, 4); s1 += __shfl_xor(s1, 8);
        s2 += __shfl_xor(s2, 1); s2 += __shfl_xor(s2, 2);
        s2 += __shfl_xor(s2, 4); s2 += __shfl_xor(s2, 8);
        const float mu = s1 * (1.0f / 128.0f);
        const float rs = rsqrtf(s2 * (1.0f / 128.0f) - mu * mu + F_LNEPS);
        float* orow = xout + bb + (size_t)n * 128;
#pragma unroll
        for (int ct = 0; ct < 8; ++ct)
          orow[16 * ct + lc] = (vals[ct] - mu) * rs * g8[ct] + be8[ct];
      }
    }
    __threadfence_block();
    __syncthreads();   // B5: layer boundary
  }
}

extern "C" void kernel_launch(void* const* d_in, const int* in_sizes, int n_in,
                              void* d_out, int out_size, void* d_ws, size_t ws_size,
                              hipStream_t stream) {
  const float* G    = (const float*)d_in[0];
  const int*   msk  = (const int*)d_in[1];
  const float* r3   = (const float*)d_in[2];
  const float* swg  = (const float*)d_in[3];
  const float* Win  = (const float*)d_in[4];
  const float* bin  = (const float*)d_in[5];
  const float* Wout = (const float*)d_in[6];
  const float* bout = (const float*)d_in[7];
  const float* lng  = (const float*)d_in[8];
  const float* lnb  = (const float*)d_in[9];
  float* xout = (float*)d_out;

  const int B = in_sizes[0] / (128 * 128);
  const bool ws_ok = ws_size >= (WTI_ELEMS + WTO_ELEMS) * sizeof(ushort_t);
  ushort_t* wtI = (ushort_t*)d_ws;
  ushort_t* wtO = wtI + WTI_ELEMS;

  if (ws_ok) {
    prep_weights<<<dim3(384), dim3(256), 0, stream>>>(Win, Wout, wtI, wtO);
    hipFuncSetAttribute(reinterpret_cast<const void*>(ngatt_mfma<true>),
                        hipFuncAttributeMaxDynamicSharedMemorySize, LDS_BYTES);
    ngatt_mfma<true><<<dim3(B), dim3(512), LDS_BYTES, stream>>>(
        G, msk, r3, swg, Win, bin, Wout, bout, lng, lnb, wtI, wtO, xout);
  } else {
    hipFuncSetAttribute(reinterpret_cast<const void*>(ngatt_mfma<false>),
                        hipFuncAttributeMaxDynamicSharedMemorySize, LDS_BYTES);
    ngatt_mfma<false><<<dim3(B), dim3(512), LDS_BYTES, stream>>>(
        G, msk, r3, swg, Win, bin, Wout, bout, lng, lnb, nullptr, nullptr, xout);
  }
}